// Round 4
// baseline (189.529 us; speedup 1.0000x reference)
//
#include <hip/hip_runtime.h>
#include <hip/hip_bf16.h>

#define GATE 512
#define MROWS 256
#define NTOT 120581

#define BM 64          // rows per block
#define BNBLK 256      // cols per block (64 per wave)
#define ASTRIDE 520    // ushorts per A row: 512 + 8 pad (1040 B) -> conflict-free

typedef __attribute__((ext_vector_type(8))) short short8;   // 8 bf16
typedef __attribute__((ext_vector_type(4))) float  f32x4;

struct GemmParams {
    const float* W[10];
    const float* p[10];
    const float* bias[10];
};

__device__ __forceinline__ short bf16bits(float x) {
    __hip_bfloat16 h = __float2bfloat16(x);   // RTNE
    return *reinterpret_cast<short*>(&h);
}

__global__ void emb_to_bf16(const float* __restrict__ emb,
                            unsigned short* __restrict__ o) {
    int i = (blockIdx.x * blockDim.x + threadIdx.x) * 8;
    f32x4 a = *(const f32x4*)(emb + i);
    f32x4 b = *(const f32x4*)(emb + i + 4);
    short8 r;
#pragma unroll
    for (int j = 0; j < 4; ++j) { r[j] = bf16bits(a[j]); r[4 + j] = bf16bits(b[j]); }
    *(short8*)(o + i) = r;
}

// Block: 64 rows x 256 cols. Wave w owns cols [w*64,+64), all 64 rows.
// A (64 x 512 bf16) staged ONCE into LDS -> single barrier; then a fully
// unrolled, barrier-free K-loop streams B (W rows, fp32) from global with
// compiler-counted vmcnt waits. bid&3 = m-block so the 4 blocks sharing a
// W panel run concurrently on different XCDs (L3 serves, HBM once).
__global__ __launch_bounds__(256, 2) void gate_gemm(GemmParams P,
                                                    const unsigned short* __restrict__ embw,
                                                    float* __restrict__ out)
{
    constexpr int kStarts[11] = {0, 1728, 1792, 38656, 38720, 75584,
                                 75648, 112512, 112576, 120576, 120581};
    __shared__ unsigned short Atile[BM * ASTRIDE];   // 66.56 KB

    const int t    = threadIdx.x;
    const int lane = t & 63;
    const int wave = t >> 6;
    const int lr   = lane & 15;   // frag col (B/C) / frag row (A)
    const int lg   = lane >> 4;   // k-group / C row-group

    const int mblk   = blockIdx.x & 3;
    const int npanel = blockIdx.x >> 2;
    const int mbase  = mblk * BM;

    // Per-lane column metadata, 4 N-fragments
    const float* wrow[4];
    float pv[4], bv[4];
    bool  valid[4];
    int   ncol[4];
#pragma unroll
    for (int nf = 0; nf < 4; ++nf) {
        int n = npanel * BNBLK + wave * 64 + nf * 16 + lr;
        ncol[nf]  = n;
        valid[nf] = n < NTOT;
        int nc = valid[nf] ? n : NTOT - 1;
        int tt = 0;
#pragma unroll
        for (int i = 1; i < 10; ++i) tt += (nc >= kStarts[i]);
        int r = nc - kStarts[tt];
        wrow[nf] = P.W[tt] + (size_t)r * GATE + lg * 8;
        pv[nf]   = P.p[tt][r];
        bv[nf]   = P.bias[tt][r];
    }

    // ---- Stage A once: one global_load_lds per row per wave (1 KB = full row).
    // LDS row r at byte rlocal*1040; HW writes firstlane-base + lane*16.
#pragma unroll
    for (int i = 0; i < 16; ++i) {
        const int rl = i * 4 + wave;
        const unsigned short* src = embw + (size_t)(mbase + rl) * GATE + lane * 8;
        unsigned short* dst = &Atile[rl * ASTRIDE] + lane * 8;
        __builtin_amdgcn_global_load_lds(
            (const __attribute__((address_space(1))) void*)src,
            (__attribute__((address_space(3))) void*)dst, 16, 0, 0);
    }

    f32x4 acc[4][4];
#pragma unroll
    for (int i = 0; i < 4; ++i)
#pragma unroll
        for (int j = 0; j < 4; ++j) acc[i][j] = (f32x4){0.f, 0.f, 0.f, 0.f};

    f32x4 Bcur[4][2], Bnxt[4][2];
    auto loadB = [&](f32x4 (&B)[4][2], int ks) {
#pragma unroll
        for (int nf = 0; nf < 4; ++nf) {
            B[nf][0] = *(const f32x4*)(wrow[nf] + ks * 32);
            B[nf][1] = *(const f32x4*)(wrow[nf] + ks * 32 + 4);
        }
    };

    loadB(Bcur, 0);          // B for step 0 (counted wait at first use)
    __syncthreads();         // the ONLY barrier: A tile ready

    // A frag base (ushort idx): row = mf*16+lr, unit = ks*4+lg
    const int abase = lr * ASTRIDE + lg * 8;

#pragma unroll
    for (int ks = 0; ks < 16; ++ks) {
        if (ks < 15) loadB(Bnxt, ks + 1);   // barrier-free prefetch

        short8 bfrag[4];
#pragma unroll
        for (int nf = 0; nf < 4; ++nf)
#pragma unroll
            for (int j = 0; j < 4; ++j) {
                bfrag[nf][j]     = bf16bits(Bcur[nf][0][j]);
                bfrag[nf][4 + j] = bf16bits(Bcur[nf][1][j]);
            }

#pragma unroll
        for (int mf = 0; mf < 4; ++mf) {
            short8 afrag = *(const short8*)(&Atile[abase + mf * 16 * ASTRIDE + ks * 32]);
#pragma unroll
            for (int nf = 0; nf < 4; ++nf)
                acc[mf][nf] = __builtin_amdgcn_mfma_f32_16x16x32_bf16(
                    afrag, bfrag[nf], acc[mf][nf], 0, 0, 0);
        }

        if (ks < 15) {
#pragma unroll
            for (int nf = 0; nf < 4; ++nf) {
                Bcur[nf][0] = Bnxt[nf][0];
                Bcur[nf][1] = Bnxt[nf][1];
            }
        }
    }

    // Epilogue: sigmoid(x+b)*p. C/D map: col = lane&15, row = (lane>>4)*4 + reg.
    // nf INNERMOST so each row's 256 B goes out in 4 back-to-back stores
    // (write-combine window -> full-line HBM writes).
#pragma unroll
    for (int mf = 0; mf < 4; ++mf) {
#pragma unroll
        for (int q = 0; q < 4; ++q) {
            const int m = mbase + mf * 16 + lg * 4 + q;
            float* orow = out + (size_t)m * NTOT;
#pragma unroll
            for (int nf = 0; nf < 4; ++nf) {
                if (!valid[nf]) continue;
                float x   = acc[mf][nf][q] + bv[nf];
                float e   = __expf(-x);
                float eta = __builtin_amdgcn_rcpf(1.0f + e);
                orow[ncol[nf]] = eta * pv[nf];
            }
        }
    }
}

extern "C" void kernel_launch(void* const* d_in, const int* in_sizes, int n_in,
                              void* d_out, int out_size, void* d_ws, size_t ws_size,
                              hipStream_t stream) {
    const float* emb = (const float*)d_in[0];
    GemmParams P;
    for (int i = 0; i < 10; ++i) {
        P.p[i]    = (const float*)d_in[1 + 3 * i];
        P.W[i]    = (const float*)d_in[2 + 3 * i];
        P.bias[i] = (const float*)d_in[3 + 3 * i];
    }

    unsigned short* embw = (unsigned short*)d_ws;   // 256 KB
    emb_to_bf16<<<(MROWS * GATE) / (256 * 8), 256, 0, stream>>>(emb, embw);

    int npanels = (NTOT + BNBLK - 1) / BNBLK;   // 472
    gate_gemm<<<npanels * 4, 256, 0, stream>>>(P, embw, (float*)d_out);
}